// Round 1
// baseline (44.081 us; speedup 1.0000x reference)
//
#include <hip/hip_runtime.h>

// Problem constants (from reference setup_inputs):
//   cls_embedding: [N=50048, H=1024] f32
//   W: [H,1] f32, b: [1] f32
//   length: [B=46, EACH=32] i32  -> S = 1472 segments, each len <= 64
//   target: [N] i32
// Output: logits [N] f32 then loss [1] f32, concatenated (out_size = N+1).

#define EACH_LEN 32   // length.shape[-1]

__device__ inline float wave_sum_f(float v) {
#pragma unroll
    for (int o = 32; o > 0; o >>= 1) v += __shfl_xor(v, o, 64);
    return v;
}
__device__ inline float wave_max_f(float v) {
#pragma unroll
    for (int o = 32; o > 0; o >>= 1) v = fmaxf(v, __shfl_xor(v, o, 64));
    return v;
}
__device__ inline int wave_sum_i(int v) {
#pragma unroll
    for (int o = 32; o > 0; o >>= 1) v += __shfl_xor(v, o, 64);
    return v;
}
__device__ inline int wave_max_i(int v) {
#pragma unroll
    for (int o = 32; o > 0; o >>= 1) v = max(v, __shfl_xor(v, o, 64));
    return v;
}

// One wave per row: logits[row] = dot(A[row,:], W) + b
__global__ __launch_bounds__(256) void matvec_kernel(
    const float* __restrict__ A, const float* __restrict__ W,
    const float* __restrict__ b, float* __restrict__ out, int N) {
    const int wid  = threadIdx.x >> 6;
    const int lane = threadIdx.x & 63;
    const int row  = blockIdx.x * 4 + wid;
    if (row >= N) return;
    const float4* a4 = reinterpret_cast<const float4*>(A + (size_t)row * 1024);
    const float4* w4 = reinterpret_cast<const float4*>(W);
    float acc = 0.f;
#pragma unroll
    for (int k = 0; k < 4; ++k) {
        float4 av = a4[lane + 64 * k];
        float4 wv = w4[lane + 64 * k];
        acc = fmaf(av.x, wv.x, acc);
        acc = fmaf(av.y, wv.y, acc);
        acc = fmaf(av.z, wv.z, acc);
        acc = fmaf(av.w, wv.w, acc);
    }
    acc = wave_sum_f(acc);
    if (lane == 0) out[row] = acc + b[0];
}

// One wave per segment. Faithful to the reference double-softmax CE.
__global__ __launch_bounds__(256) void seg_loss_kernel(
    const float* __restrict__ logits, const int* __restrict__ lens,
    const int* __restrict__ tgt, float* __restrict__ contrib,
    float* __restrict__ incl, int S) {
    const int wid  = threadIdx.x >> 6;
    const int lane = threadIdx.x & 63;
    const int s    = blockIdx.x * 4 + wid;
    if (s >= S) return;

    // offset = sum(lens[0..s))
    int part = 0;
    for (int j = lane; j < s; j += 64) part += lens[j];
    const int offset = wave_sum_i(part);
    const int len = lens[s];
    const bool valid = lane < len;

    // softmax over the segment
    const float l = valid ? logits[offset + lane] : -3.402823e38f;
    const float m = wave_max_f(l);
    const float e = valid ? __expf(l - m) : 0.f;
    const float Z = wave_sum_f(e);
    const float p = e / Z;   // p in [0,1] for valid lanes

    // second logsumexp over the probabilities (valid lanes only)
    const float q = valid ? __expf(p) : 0.f;
    const float lse2 = __logf(wave_sum_f(q));

    // target: argmax over (valid ? tgt : -1), first occurrence
    const int tv = valid ? tgt[offset + lane] : -1;
    const int maxt = wave_max_i(tv);
    const unsigned long long ball = __ballot(tv == maxt);
    const int t_idx = __ffsll(ball) - 1;
    const float p_t = __shfl(p, t_idx, 64);

    const int tgt_sum = wave_sum_i(valid ? tv : 0);

    // include conditions (faithful replication)
    const int next_len = (s + 1 < S) ? lens[s + 1] : 1;
    const bool skip_next_zero = (s > 0) && (s + 1 < S) && (next_len == 0);
    const bool skip_no_pos = (((s + 1) % EACH_LEN) == 0) && (tgt_sum <= 0);
    const bool include = (len > 0) && !skip_next_zero && !skip_no_pos;

    if (lane == 0) {
        contrib[s] = include ? (lse2 - p_t) : 0.f;
        incl[s]    = include ? 1.f : 0.f;
    }
}

__global__ __launch_bounds__(256) void reduce_kernel(
    const float* __restrict__ contrib, const float* __restrict__ incl,
    float* __restrict__ out_loss, int S) {
    float a = 0.f, c = 0.f;
    for (int i = threadIdx.x; i < S; i += 256) {
        a += contrib[i];
        c += incl[i];
    }
    a = wave_sum_f(a);
    c = wave_sum_f(c);
    __shared__ float wa[4], wc[4];
    const int wid = threadIdx.x >> 6, lane = threadIdx.x & 63;
    if (lane == 0) { wa[wid] = a; wc[wid] = c; }
    __syncthreads();
    if (threadIdx.x == 0) {
        const float A = wa[0] + wa[1] + wa[2] + wa[3];
        const float C = wc[0] + wc[1] + wc[2] + wc[3];
        const float denom = (C > 0.f) ? C : 1e-4f;
        out_loss[0] = A / denom;
    }
}

extern "C" void kernel_launch(void* const* d_in, const int* in_sizes, int n_in,
                              void* d_out, int out_size, void* d_ws, size_t ws_size,
                              hipStream_t stream) {
    const float* A   = (const float*)d_in[0];   // cls_embedding [N,H]
    const float* W   = (const float*)d_in[1];   // [H,1]
    const float* b   = (const float*)d_in[2];   // [1]
    const int*  lens = (const int*)d_in[3];     // [S] (flattened [B,EACH])
    const int*  tgt  = (const int*)d_in[4];     // [N]

    const int H = in_sizes[1];                  // 1024
    const int N = in_sizes[0] / H;              // 50048
    const int S = in_sizes[3];                  // 1472

    float* logits = (float*)d_out;              // [N]
    float* loss   = logits + N;                 // [1]

    float* contrib = (float*)d_ws;              // [S]
    float* incl    = contrib + S;               // [S]

    matvec_kernel<<<(N + 3) / 4, 256, 0, stream>>>(A, W, b, logits, N);
    seg_loss_kernel<<<(S + 3) / 4, 256, 0, stream>>>(logits, lens, tgt, contrib, incl, S);
    reduce_kernel<<<1, 256, 0, stream>>>(contrib, incl, loss, S);
}

// Round 2
// 38.999 us; speedup vs baseline: 1.1303x; 1.1303x over previous
//
#include <hip/hip_runtime.h>

// Problem: logits = cls_embedding[N=50048,H=1024] @ W[1024] + b  (fp32),
// then per-segment double-softmax CE over S=1472 ragged segments (len<=64),
// mean over included segments. Output: logits[N] ++ loss[1].

#define EACH_LEN 32   // length.shape[-1]

__device__ inline float wave_sum_f(float v) {
#pragma unroll
    for (int o = 32; o > 0; o >>= 1) v += __shfl_xor(v, o, 64);
    return v;
}
__device__ inline float wave_max_f(float v) {
#pragma unroll
    for (int o = 32; o > 0; o >>= 1) v = fmaxf(v, __shfl_xor(v, o, 64));
    return v;
}
__device__ inline int wave_sum_i(int v) {
#pragma unroll
    for (int o = 32; o > 0; o >>= 1) v += __shfl_xor(v, o, 64);
    return v;
}
__device__ inline int wave_max_i(int v) {
#pragma unroll
    for (int o = 32; o > 0; o >>= 1) v = max(v, __shfl_xor(v, o, 64));
    return v;
}

// One block = two segments (paired long+short for load balance when S%16==0:
// lens pattern (i%16+1)*4 makes every pair sum to 68 rows). Block computes the
// matvec for all its rows, then waves 0/1 do the two segment losses from LDS.
__global__ __launch_bounds__(256) void fused_kernel(
    const float* __restrict__ A, const float* __restrict__ W,
    const float* __restrict__ b, const int* __restrict__ lens,
    const int* __restrict__ tgt, float* __restrict__ logits,
    float* __restrict__ contrib, float* __restrict__ incl, int S) {
    const int tid = threadIdx.x, wid = tid >> 6, lane = tid & 63;

    int s0, s1;
    if ((S & 15) == 0) {                    // balanced pairing (permutation)
        const int g = blockIdx.x >> 3, j = blockIdx.x & 7;
        s0 = g * 16 + j;
        s1 = g * 16 + 15 - j;
    } else {                                // generic fallback
        s0 = blockIdx.x * 2;
        s1 = (s0 + 1 < S) ? s0 + 1 : -1;
    }

    // offsets = prefix sums of lens
    const int hi = max(s0, s1);
    int p0 = 0, p1 = 0;
    for (int j = tid; j < hi; j += 256) {
        const int l = lens[j];
        if (j < s0) p0 += l;
        if (j < s1) p1 += l;
    }
    p0 = wave_sum_i(p0);
    p1 = wave_sum_i(p1);
    __shared__ int w0[4], w1[4];
    if (lane == 0) { w0[wid] = p0; w1[wid] = p1; }
    __syncthreads();
    const int off0 = w0[0] + w0[1] + w0[2] + w0[3];
    const int off1 = w1[0] + w1[1] + w1[2] + w1[3];
    const int len0 = lens[s0];
    const int len1 = (s1 >= 0) ? lens[s1] : 0;

    // W into registers (4 KB, wave-replicated; L1-resident anyway)
    const float4* w4 = reinterpret_cast<const float4*>(W);
    const float4 wv0 = w4[lane], wv1 = w4[lane + 64],
                 wv2 = w4[lane + 128], wv3 = w4[lane + 192];
    const float bias = b[0];

    __shared__ float slog[128];
    const int R = len0 + len1;
    for (int r = wid; r < R; r += 4) {
        const int row = (r < len0) ? (off0 + r) : (off1 + (r - len0));
        const float4* a4 = reinterpret_cast<const float4*>(A + (size_t)row * 1024);
        float acc = 0.f;
        float4 av;
        av = a4[lane];
        acc = fmaf(av.x, wv0.x, acc); acc = fmaf(av.y, wv0.y, acc);
        acc = fmaf(av.z, wv0.z, acc); acc = fmaf(av.w, wv0.w, acc);
        av = a4[lane + 64];
        acc = fmaf(av.x, wv1.x, acc); acc = fmaf(av.y, wv1.y, acc);
        acc = fmaf(av.z, wv1.z, acc); acc = fmaf(av.w, wv1.w, acc);
        av = a4[lane + 128];
        acc = fmaf(av.x, wv2.x, acc); acc = fmaf(av.y, wv2.y, acc);
        acc = fmaf(av.z, wv2.z, acc); acc = fmaf(av.w, wv2.w, acc);
        av = a4[lane + 192];
        acc = fmaf(av.x, wv3.x, acc); acc = fmaf(av.y, wv3.y, acc);
        acc = fmaf(av.z, wv3.z, acc); acc = fmaf(av.w, wv3.w, acc);
        acc = wave_sum_f(acc);
        if (lane == 0) {
            const float v = acc + bias;
            slog[r] = v;
            logits[row] = v;
        }
    }
    __syncthreads();

    // waves 0/1: per-segment double-softmax CE
    if (wid < 2) {
        const int s = wid ? s1 : s0;
        if (s >= 0) {
            const int len  = wid ? len1 : len0;
            const int off  = wid ? off1 : off0;
            const int base = wid ? len0 : 0;
            const bool valid = lane < len;

            const float l = valid ? slog[base + lane] : -3.402823e38f;
            const float m = wave_max_f(l);
            const float e = valid ? __expf(l - m) : 0.f;
            const float Z = wave_sum_f(e);
            const float p = e / Z;

            const float q = valid ? __expf(p) : 0.f;
            const float lse2 = __logf(wave_sum_f(q));

            const int tv = valid ? tgt[off + lane] : -1;
            const int maxt = wave_max_i(tv);
            const unsigned long long ball = __ballot(tv == maxt);
            const int t_idx = __ffsll(ball) - 1;
            const float p_t = __shfl(p, t_idx, 64);

            const int tgt_sum = wave_sum_i(valid ? tv : 0);

            const int next_len = (s + 1 < S) ? lens[s + 1] : 1;
            const bool skip_next_zero = (s > 0) && (s + 1 < S) && (next_len == 0);
            const bool skip_no_pos = (((s + 1) % EACH_LEN) == 0) && (tgt_sum <= 0);
            const bool include = (len > 0) && !skip_next_zero && !skip_no_pos;

            if (lane == 0) {
                contrib[s] = include ? (lse2 - p_t) : 0.f;
                incl[s]    = include ? 1.f : 0.f;
            }
        }
    }
}

__global__ __launch_bounds__(256) void reduce_kernel(
    const float* __restrict__ contrib, const float* __restrict__ incl,
    float* __restrict__ out_loss, int S) {
    float a = 0.f, c = 0.f;
    for (int i = threadIdx.x; i < S; i += 256) {
        a += contrib[i];
        c += incl[i];
    }
    a = wave_sum_f(a);
    c = wave_sum_f(c);
    __shared__ float wa[4], wc[4];
    const int wid = threadIdx.x >> 6, lane = threadIdx.x & 63;
    if (lane == 0) { wa[wid] = a; wc[wid] = c; }
    __syncthreads();
    if (threadIdx.x == 0) {
        const float A = wa[0] + wa[1] + wa[2] + wa[3];
        const float C = wc[0] + wc[1] + wc[2] + wc[3];
        const float denom = (C > 0.f) ? C : 1e-4f;
        out_loss[0] = A / denom;
    }
}

extern "C" void kernel_launch(void* const* d_in, const int* in_sizes, int n_in,
                              void* d_out, int out_size, void* d_ws, size_t ws_size,
                              hipStream_t stream) {
    const float* A   = (const float*)d_in[0];   // cls_embedding [N,H]
    const float* W   = (const float*)d_in[1];   // [H,1]
    const float* b   = (const float*)d_in[2];   // [1]
    const int*  lens = (const int*)d_in[3];     // [S]
    const int*  tgt  = (const int*)d_in[4];     // [N]

    const int H = in_sizes[1];                  // 1024
    const int N = in_sizes[0] / H;              // 50048
    const int S = in_sizes[3];                  // 1472

    float* logits = (float*)d_out;              // [N]
    float* loss   = logits + N;                 // [1]

    float* contrib = (float*)d_ws;              // [S]
    float* incl    = contrib + S;               // [S]

    const int nblk = (S + 1) / 2;
    fused_kernel<<<nblk, 256, 0, stream>>>(A, W, b, lens, tgt,
                                           logits, contrib, incl, S);
    reduce_kernel<<<1, 256, 0, stream>>>(contrib, incl, loss, S);
}